// Round 20
// baseline (184.151 us; speedup 1.0000x reference)
//
#include <hip/hip_runtime.h>
#include <hip/hip_bf16.h>

// ---------------------------------------------------------------------------
// Fused causal MHA forward: x[B,T,C] fp32, w_qkv[3C,C] fp32, w_out[C,C] fp32
// B=4 T=2048 C=1024 H=16 hd=64.  All matmuls in bf16 MFMA, fp32 accumulate.
// fused convert | GEMM qkv 256x256 (V^T fused epilogue) | flash-attn | proj.
// R19: gemm1 tile 256x128 -> 256x256: A-panel re-fetch halves (403->201MB).
// ---------------------------------------------------------------------------

typedef __attribute__((ext_vector_type(8))) short bf16x8;
typedef __attribute__((ext_vector_type(4))) float f32x4;
typedef __attribute__((ext_vector_type(16))) float f32x16;
typedef __attribute__((ext_vector_type(2))) unsigned uint2v;

#define GLOBAL_AS __attribute__((address_space(1)))
#define LDS_AS __attribute__((address_space(3)))

__device__ __forceinline__ unsigned short f2b_rne(float f) {
  unsigned u = __float_as_uint(f);
  unsigned r = u + 0x7fffu + ((u >> 16) & 1u);
  return (unsigned short)(r >> 16);
}

__device__ __forceinline__ unsigned cvt_pk_bf16(float lo, float hi) {
  unsigned r;
  asm("v_cvt_pk_bf16_f32 %0, %1, %2" : "=v"(r) : "v"(lo), "v"(hi));
  return r;
}

__device__ __forceinline__ void gload_lds16(const void* g, void* l) {
  __builtin_amdgcn_global_load_lds((const GLOBAL_AS void*)g, (LDS_AS void*)l, 16, 0, 0);
}

// ---------------------------------------------------------------------------
// Fused fp32 -> bf16 conversion of all three inputs.
// ---------------------------------------------------------------------------
__global__ void fused_convert(const float* __restrict__ x,
                              const float* __restrict__ wqkv,
                              const float* __restrict__ wout,
                              unsigned short* __restrict__ xb,
                              unsigned short* __restrict__ wqkvb,
                              unsigned short* __restrict__ woutb) {
  const int nx = 8192 * 1024 / 4, nq = 3072 * 1024 / 4, nw = 1024 * 1024 / 4;
  const int ntot = nx + nq + nw;
  int i = blockIdx.x * blockDim.x + threadIdx.x;
  int stride = gridDim.x * blockDim.x;
  for (; i < ntot; i += stride) {
    const float* src;
    unsigned short* dst;
    int j = i;
    if (j < nx) {
      src = x; dst = xb;
    } else if ((j -= nx) < nq) {
      src = wqkv; dst = wqkvb;
    } else {
      j -= nq; src = wout; dst = woutb;
    }
    float4 v = reinterpret_cast<const float4*>(src)[j];
    ushort4 o;
    o.x = f2b_rne(v.x); o.y = f2b_rne(v.y);
    o.z = f2b_rne(v.z); o.w = f2b_rne(v.w);
    reinterpret_cast<ushort4*>(dst)[j] = o;
  }
}

// ---------------------------------------------------------------------------
// QKV GEMM: qkv[8192,3072] = xb * wqkv^T.  256x256 tile, 8 waves (4Mx2N,
// each wave 64x128), BK=64, mfma_32x32x16, counted-vmcnt (8 loads/wave).
// V-blocks (n0>=2048) stored TRANSPOSED into vt via 64KB LDS bounce x2.
// ---------------------------------------------------------------------------
__global__ __launch_bounds__(512)
void gemm_qkv256(const unsigned short* __restrict__ A,
                 const unsigned short* __restrict__ B,
                 unsigned short* __restrict__ qkv,
                 unsigned short* __restrict__ vt) {
  const int K = 1024, N = 3072;
  __shared__ __align__(16) unsigned short As[2][256 * 64];  // 32KB per buf
  __shared__ __align__(16) unsigned short Bs[2][256 * 64];

  const int tid = threadIdx.x, wid = tid >> 6, lane = tid & 63;
  const int l31 = lane & 31, h = lane >> 5;
  // grid 384 = 8 XCDs x 48 (bijective)
  const int wgid = ((int)blockIdx.x & 7) * 48 + ((int)blockIdx.x >> 3);
  const int bx = wgid % 12, by = wgid / 12;
  const int m0 = by * 256, n0 = bx * 256;
  const int wr = wid >> 1, wc = wid & 1;  // wave: rows [wr*64,+64) cols [wc*128,+128)

  auto stage = [&](int t, int buf) {
    const int k0 = t * 64;
    const int r8 = lane >> 3;
    const int blk = (lane & 7) ^ r8;
#pragma unroll
    for (int pp = 0; pp < 4; ++pp) {  // A: 32 chunks of 8 rows
      int chunk = wid * 4 + pp;
      int row = chunk * 8 + r8;
      gload_lds16(A + (size_t)(m0 + row) * K + k0 + blk * 8,
                  &As[buf][chunk * 512]);
    }
#pragma unroll
    for (int pp = 0; pp < 4; ++pp) {  // B: 32 chunks of 8 rows
      int chunk = wid * 4 + pp;
      int row = chunk * 8 + r8;
      gload_lds16(B + (size_t)(n0 + row) * K + k0 + blk * 8,
                  &Bs[buf][chunk * 512]);
    }
  };

  f32x16 acc[2][4] = {};  // rows: mi*32 frags, cols: ni*32 frags (128 wide)

  stage(0, 0);

  int cur = 0;
  for (int t = 0; t < 16; ++t) {
    __builtin_amdgcn_s_barrier();
    if (t + 1 < 16) {
      stage(t + 1, cur ^ 1);
      asm volatile("s_waitcnt vmcnt(8)" ::: "memory");  // waits tile t's loads
    } else {
      asm volatile("s_waitcnt vmcnt(0)" ::: "memory");
    }
    __builtin_amdgcn_s_barrier();
    __builtin_amdgcn_sched_barrier(0);

    __builtin_amdgcn_s_setprio(1);
#pragma unroll
    for (int ks = 0; ks < 4; ++ks) {
      bf16x8 af[2], bfr[4];
#pragma unroll
      for (int mi = 0; mi < 2; ++mi) {
        int row = wr * 64 + mi * 32 + l31;
        int chunk = (ks * 2 + h) ^ (row & 7);
        af[mi] = *(const bf16x8*)&As[cur][row * 64 + chunk * 8];
      }
#pragma unroll
      for (int ni = 0; ni < 4; ++ni) {
        int row = wc * 128 + ni * 32 + l31;
        int chunk = (ks * 2 + h) ^ (row & 7);
        bfr[ni] = *(const bf16x8*)&Bs[cur][row * 64 + chunk * 8];
      }
#pragma unroll
      for (int mi = 0; mi < 2; ++mi)
#pragma unroll
        for (int ni = 0; ni < 4; ++ni)
          acc[mi][ni] = __builtin_amdgcn_mfma_f32_32x32x16_bf16(
              af[mi], bfr[ni], acc[mi][ni], 0, 0, 0);
    }
    __builtin_amdgcn_s_setprio(0);
    cur ^= 1;
  }

  if (n0 >= 2048) {
    // ---- fused V^T: two 128-col halves bounce through 64KB LDS ----
    unsigned short(*Ts)[128] = (unsigned short(*)[128]) & As[0][0];
    const int bq = m0 >> 11, toff = m0 & 2047;
#pragma unroll
    for (int hh2 = 0; hh2 < 2; ++hh2) {
      __syncthreads();  // staged-LDS reads (or prev half's Ts reads) done
      if (wc == hh2) {
#pragma unroll
        for (int mi = 0; mi < 2; ++mi)
#pragma unroll
          for (int ni = 0; ni < 4; ++ni)
#pragma unroll
            for (int reg = 0; reg < 16; ++reg) {
              int row = wr * 64 + mi * 32 + (reg & 3) + 8 * (reg >> 2) + 4 * h;
              int cl = ni * 32 + l31;
              Ts[row][((cl >> 3) ^ (row & 15)) * 8 + (cl & 7)] =
                  f2b_rne(acc[mi][ni][reg]);
            }
      }
      __syncthreads();
      const int cl = tid >> 2, tb = tid & 3;
      const int ch = (n0 - 2048) + hh2 * 128 + cl;
      const int hh = ch >> 6, d = ch & 63;
      unsigned short* dst =
          vt + ((size_t)(bq * 16 + hh) * 64 + d) * 2048 + toff;
#pragma unroll
      for (int i = 0; i < 8; ++i) {
        int t0 = tb * 64 + i * 8;
        union { unsigned short s[8]; bf16x8 v; } o;
#pragma unroll
        for (int k = 0; k < 8; ++k) {
          int row = t0 + k;
          o.s[k] = Ts[row][(((cl >> 3) ^ (row & 15)) * 8) + (cl & 7)];
        }
        *(bf16x8*)(dst + t0) = o.v;
      }
    }
  } else {
#pragma unroll
    for (int mi = 0; mi < 2; ++mi)
#pragma unroll
      for (int ni = 0; ni < 4; ++ni)
#pragma unroll
        for (int reg = 0; reg < 16; ++reg) {
          int row = m0 + wr * 64 + mi * 32 + (reg & 3) + 8 * (reg >> 2) + 4 * h;
          int col = n0 + wc * 128 + ni * 32 + l31;
          qkv[(size_t)row * N + col] = f2b_rne(acc[mi][ni][reg]);
        }
  }
}

// ---------------------------------------------------------------------------
// Proj GEMM: out[8192,1024] fp32 = attno * wout^T.  256x128 tile (unchanged).
// ---------------------------------------------------------------------------
__global__ __launch_bounds__(512)
void gemm_proj(const unsigned short* __restrict__ A,
               const unsigned short* __restrict__ B,
               float* __restrict__ Cout) {
  const int K = 1024, N = 1024;
  __shared__ __align__(16) unsigned short As[2][2][128 * 64];
  __shared__ __align__(16) unsigned short Bs[2][128 * 64];

  const int tid = threadIdx.x, wid = tid >> 6, lane = tid & 63;
  const int l31 = lane & 31, h = lane >> 5;
  const int NBX = N / 128;
  const int nwg8 = (int)gridDim.x >> 3;
  const int wgid = ((int)blockIdx.x & 7) * nwg8 + ((int)blockIdx.x >> 3);
  const int bx = wgid % NBX, by = wgid / NBX;
  const int m0 = by * 256, n0 = bx * 128;
  const int wr = wid >> 1, wc = wid & 1;

  auto stage = [&](int t, int buf) {
    const int k0 = t * 64;
    const int r8 = lane >> 3;
    const int blk = (lane & 7) ^ r8;
#pragma unroll
    for (int hh = 0; hh < 2; ++hh)
#pragma unroll
      for (int r = 0; r < 2; ++r) {
        int row = r * 64 + wid * 8 + r8;
        gload_lds16(A + (size_t)(m0 + hh * 128 + row) * K + k0 + blk * 8,
                    &As[buf][hh][r * 4096 + wid * 512]);
      }
#pragma unroll
    for (int r = 0; r < 2; ++r) {
      int row = r * 64 + wid * 8 + r8;
      gload_lds16(B + (size_t)(n0 + row) * K + k0 + blk * 8,
                  &Bs[buf][r * 4096 + wid * 512]);
    }
  };

  f32x16 acc[2][2] = {};

  stage(0, 0);

  int cur = 0;
  for (int t = 0; t < 16; ++t) {
    __builtin_amdgcn_s_barrier();
    if (t + 1 < 16) {
      stage(t + 1, cur ^ 1);
      asm volatile("s_waitcnt vmcnt(6)" ::: "memory");
    } else {
      asm volatile("s_waitcnt vmcnt(0)" ::: "memory");
    }
    __builtin_amdgcn_s_barrier();
    __builtin_amdgcn_sched_barrier(0);

    bf16x8 af[2][4], bfr[2][4];
#pragma unroll
    for (int mi = 0; mi < 2; ++mi) {
      int row = (wr & 1) * 64 + mi * 32 + l31;
#pragma unroll
      for (int ks = 0; ks < 4; ++ks) {
        int chunk = (ks * 2 + h) ^ (row & 7);
        af[mi][ks] = *(const bf16x8*)&As[cur][wr >> 1][row * 64 + chunk * 8];
      }
    }
#pragma unroll
    for (int ni = 0; ni < 2; ++ni) {
      int row = wc * 64 + ni * 32 + l31;
#pragma unroll
      for (int ks = 0; ks < 4; ++ks) {
        int chunk = (ks * 2 + h) ^ (row & 7);
        bfr[ni][ks] = *(const bf16x8*)&Bs[cur][row * 64 + chunk * 8];
      }
    }
    __builtin_amdgcn_s_setprio(1);
#pragma unroll
    for (int ks = 0; ks < 4; ++ks)
#pragma unroll
      for (int mi = 0; mi < 2; ++mi)
#pragma unroll
        for (int ni = 0; ni < 2; ++ni)
          acc[mi][ni] = __builtin_amdgcn_mfma_f32_32x32x16_bf16(
              af[mi][ks], bfr[ni][ks], acc[mi][ni], 0, 0, 0);
    __builtin_amdgcn_s_setprio(0);
    cur ^= 1;
  }

#pragma unroll
  for (int mi = 0; mi < 2; ++mi)
#pragma unroll
    for (int ni = 0; ni < 2; ++ni)
#pragma unroll
      for (int reg = 0; reg < 16; ++reg) {
        int row = m0 + wr * 64 + mi * 32 + (reg & 3) + 8 * (reg >> 2) + 4 * h;
        int col = n0 + wc * 64 + ni * 32 + l31;
        Cout[(size_t)row * N + col] = acc[mi][ni][reg];
      }
}

// ---------------------------------------------------------------------------
// Flash attention fwd, causal; swapped-QK^T 32x32; 64 q-rows per wave.
// Super-tile staging: 128 kv rows per barrier-pair.  (unchanged R17/R18)
// ---------------------------------------------------------------------------
__global__ __launch_bounds__(256, 2)
void attn_fwd(const unsigned short* __restrict__ qkv,
              const unsigned short* __restrict__ vt,
              unsigned short* __restrict__ out) {
  const int T = 2048, C3 = 3072;
  __shared__ __align__(16) unsigned short Ks[2][128][64];  // [kv][d] swizzled
  __shared__ __align__(16) unsigned short Vs[2][64][128];  // [d][kv] swizzled
  __shared__ float Bc[4][32];  // per-wave broadcast (wave-private)

  const int tid = threadIdx.x, w = tid >> 6, lane = tid & 63;
  const int l31 = lane & 31, h = lane >> 5;
  const int wgid = (blockIdx.x & 7) * 64 + (blockIdx.x >> 3);
  const int local = wgid & 63, xcd = wgid >> 6;
  const int qidx = local >> 3, bhl = local & 7;
  const int bh = xcd * 8 + bhl;
  const int qt = (qidx < 4) ? (7 - qidx) : (qidx - 4);
  const int b = bh >> 4, hed = bh & 15;
  const int qw = qt * 256 + w * 64;
  const size_t rowbase = (size_t)b * T * C3;
  const int hoff = hed * 64;
  const unsigned short* vbase = vt + (size_t)bh * 64 * 2048;
  const float c2 = 0.18033688f;  // 0.125 * log2(e)

  auto stageK = [&](int kv0, int buf) {
#pragma unroll
    for (int pp = 0; pp < 4; ++pp) {
      int chunk = w * 4 + pp;
      int row = chunk * 8 + (lane >> 3);
      int blk = (lane & 7) ^ (lane >> 3);
      gload_lds16(
          qkv + rowbase + (size_t)(kv0 + row) * C3 + 1024 + hoff + blk * 8,
          &Ks[buf][chunk * 8][0]);
    }
  };
  auto stageV = [&](int kv0, int buf) {
#pragma unroll
    for (int pp = 0; pp < 4; ++pp) {
      int c = w * 4 + pp;
      int d = c * 4 + (lane >> 4);
      int pos = lane & 15;
      int kvb = (pos & 8) | ((pos & 7) ^ (d & 7));
      gload_lds16(vbase + (size_t)d * 2048 + kv0 + kvb * 8,
                  &Vs[buf][c * 4][0]);
    }
  };

  bf16x8 qf0[4], qf1[4];
  {
    const unsigned short* qp0 =
        qkv + rowbase + (size_t)(qw + l31) * C3 + hoff + h * 8;
    const unsigned short* qp1 = qp0 + 32 * C3;
#pragma unroll
    for (int s = 0; s < 4; ++s) {
      qf0[s] = *(const bf16x8*)(qp0 + 16 * s);
      qf1[s] = *(const bf16x8*)(qp1 + 16 * s);
    }
  }

  f32x16 oacc0[2] = {}, oacc1[2] = {};
  float mr0 = -1e30f, mr1 = -1e30f, sum0 = 0.f, sum1 = 0.f;

  stageK(0, 0);
  stageV(0, 0);

  auto do_half = [&](f32x16 (&sacc)[2], int qx, float& mr, float& sm,
                     f32x16 (&oc)[2], bool first, int kvp, int cur, int vofs) {
    if (kvp + 64 > qx) {
      int q_abs = qx + l31;
#pragma unroll
      for (int kt = 0; kt < 2; ++kt)
#pragma unroll
        for (int r = 0; r < 16; ++r) {
          int kv_abs = kvp + kt * 32 + (r & 3) + 8 * (r >> 2) + 4 * h;
          if (kv_abs > q_abs) sacc[kt][r] = -1e30f;
        }
    }
    float mx[8];
#pragma unroll
    for (int g = 0; g < 8; ++g)
      mx[g] = fmaxf(fmaxf(sacc[g >> 2][(g & 3) * 4 + 0],
                          sacc[g >> 2][(g & 3) * 4 + 1]),
                    fmaxf(sacc[g >> 2][(g & 3) * 4 + 2],
                          sacc[g >> 2][(g & 3) * 4 + 3]));
    float tm = fmaxf(fmaxf(fmaxf(mx[0], mx[1]), fmaxf(mx[2], mx[3])),
                     fmaxf(fmaxf(mx[4], mx[5]), fmaxf(mx[6], mx[7])));
    tm = fmaxf(tm, __shfl_xor(tm, 32));
    if (first) {
      mr = tm;
    } else if (!__all(tm <= mr + 16.0f)) {
      float mnew = fmaxf(mr, tm);
      float corr = __builtin_amdgcn_exp2f((mr - mnew) * c2);
      sm *= corr;
      if (h == 0) Bc[w][l31] = corr;
      mr = mnew;
      asm volatile("s_waitcnt lgkmcnt(0)" ::: "memory");
#pragma unroll
      for (int r = 0; r < 16; ++r) {
        float cr = Bc[w][(r & 3) + 8 * (r >> 2) + 4 * h];
        oc[0][r] *= cr;
        oc[1][r] *= cr;
      }
    }
    float m2 = mr * c2;
    float s0 = 0.f, s1 = 0.f, s2 = 0.f, s3 = 0.f;
#pragma unroll
    for (int kt = 0; kt < 2; ++kt)
#pragma unroll
      for (int r = 0; r < 16; r += 4) {
        float p0 = __builtin_amdgcn_exp2f(fmaf(sacc[kt][r + 0], c2, -m2));
        float p1 = __builtin_amdgcn_exp2f(fmaf(sacc[kt][r + 1], c2, -m2));
        float p2 = __builtin_amdgcn_exp2f(fmaf(sacc[kt][r + 2], c2, -m2));
        float p3 = __builtin_amdgcn_exp2f(fmaf(sacc[kt][r + 3], c2, -m2));
        sacc[kt][r + 0] = p0; sacc[kt][r + 1] = p1;
        sacc[kt][r + 2] = p2; sacc[kt][r + 3] = p3;
        s0 += p0; s1 += p1; s2 += p2; s3 += p3;
      }
    float sl = (s0 + s1) + (s2 + s3);
    sm += sl + __shfl_xor(sl, 32);
    unsigned pk[16];
#pragma unroll
    for (int kt = 0; kt < 2; ++kt)
#pragma unroll
      for (int r = 0; r < 16; r += 2)
        pk[kt * 8 + (r >> 1)] = cvt_pk_bf16(sacc[kt][r], sacc[kt][r + 1]);
    __builtin_amdgcn_s_setprio(1);
#pragma unroll
    for (int sg = 0; sg < 4; ++sg) {
      const int kt = sg >> 1, s = sg & 1;
      const int base = kt * 8 + 4 * s;
      uint2v r02 = __builtin_amdgcn_permlane32_swap(pk[base], pk[base + 2],
                                                    false, false);
      uint2v r13 = __builtin_amdgcn_permlane32_swap(pk[base + 1], pk[base + 3],
                                                    false, false);
      union { unsigned u[4]; bf16x8 v; } Afr;
      Afr.u[0] = r02.x; Afr.u[1] = r13.x;
      Afr.u[2] = r02.y; Afr.u[3] = r13.y;
#pragma unroll
      for (int dt = 0; dt < 2; ++dt) {
        int d = dt * 32 + l31;
        int blk = (2 * sg + h) ^ (d & 7);
        bf16x8 vf = *(const bf16x8*)&Vs[cur][d][vofs + blk * 8];
        oc[dt] = __builtin_amdgcn_mfma_f32_32x32x16_bf16(Afr.v, vf,
                                                         oc[dt], 0, 0, 0);
      }
    }
    __builtin_amdgcn_s_setprio(0);
  };

  int cur = 0;
  const int nsup = 2 * qt + 2;  // super-tiles of 128 kv
  for (int t = 0; t < nsup; ++t) {
    const int kv0 = t * 128;
    __builtin_amdgcn_s_barrier();
    if (t + 1 < nsup) {
      stageK(kv0 + 128, cur ^ 1);
      stageV(kv0 + 128, cur ^ 1);
      asm volatile("s_waitcnt vmcnt(8)" ::: "memory");
    } else {
      asm volatile("s_waitcnt vmcnt(0)" ::: "memory");
    }
    __builtin_amdgcn_s_barrier();
    __builtin_amdgcn_sched_barrier(0);

#pragma unroll
    for (int p = 0; p < 2; ++p) {
      const int kvp = kv0 + p * 64;
      if (kvp <= qw) {
        f32x16 sacc0[2] = {}, sacc1[2] = {};
        __builtin_amdgcn_s_setprio(1);
#pragma unroll
        for (int s = 0; s < 4; ++s) {
#pragma unroll
          for (int kt = 0; kt < 2; ++kt) {
            int row = kt * 32 + l31;
            int blk = (2 * s + h) ^ (row & 7);
            bf16x8 kf = *(const bf16x8*)&Ks[cur][p * 64 + row][blk * 8];
            sacc0[kt] = __builtin_amdgcn_mfma_f32_32x32x16_bf16(
                kf, qf0[s], sacc0[kt], 0, 0, 0);
            sacc1[kt] = __builtin_amdgcn_mfma_f32_32x32x16_bf16(
                kf, qf1[s], sacc1[kt], 0, 0, 0);
          }
        }
        __builtin_amdgcn_s_setprio(0);
        const bool first = (t == 0 && p == 0);
        do_half(sacc0, qw, mr0, sum0, oacc0, first, kvp, cur, p * 64);
        do_half(sacc1, qw + 32, mr1, sum1, oacc1, first, kvp, cur, p * 64);
      }
    }
    cur ^= 1;
  }

  // epilogue (Bc is wave-private: lgkmcnt suffices, no barriers)
#pragma unroll
  for (int X = 0; X < 2; ++X) {
    float sm = X ? sum1 : sum0;
    if (h == 0) Bc[w][l31] = 1.0f / sm;
    asm volatile("s_waitcnt lgkmcnt(0)" ::: "memory");
#pragma unroll
    for (int r = 0; r < 16; ++r) {
      int ql = (r & 3) + 8 * (r >> 2) + 4 * h;
      float inv = Bc[w][ql];
      int q_abs = qw + 32 * X + ql;
#pragma unroll
      for (int dt = 0; dt < 2; ++dt) {
        float v = (X ? oacc1 : oacc0)[dt][r] * inv;
        out[(size_t)(b * T + q_abs) * 1024 + hoff + dt * 32 + l31] =
            f2b_rne(v);
      }
    }
  }
}

// ---------------------------------------------------------------------------
extern "C" void kernel_launch(void* const* d_in, const int* in_sizes, int n_in,
                              void* d_out, int out_size, void* d_ws,
                              size_t ws_size, hipStream_t stream) {
  const float* x = (const float*)d_in[0];      // [4,2048,1024]
  const float* w_qkv = (const float*)d_in[1];  // [3072,1024]
  const float* w_out = (const float*)d_in[2];  // [1024,1024]
  float* out = (float*)d_out;                  // [4,2048,1024] fp32

  const int M = 8192, C = 1024, C3 = 3072;

  unsigned short* xb = (unsigned short*)d_ws;      // M*C  (reused as attno)
  unsigned short* wqkvb = xb + (size_t)M * C;      // C3*C
  unsigned short* woutb = wqkvb + (size_t)C3 * C;  // C*C
  unsigned short* qkv = woutb + (size_t)C * C;     // M*C3 (V region unused)
  unsigned short* vtb = qkv + (size_t)M * C3;      // B*H*64*T = M*C
  unsigned short* attno = xb;                      // alias: xb dead post-GEMM1

  fused_convert<<<2048, 256, 0, stream>>>(x, w_qkv, w_out, xb, wqkvb, woutb);

  gemm_qkv256<<<384, 512, 0, stream>>>(xb, wqkvb, qkv, vtb);

  attn_fwd<<<512, 256, 0, stream>>>(qkv, vtb, attno);

  gemm_proj<<<256, 512, 0, stream>>>(attno, woutb, out);
}

// Round 21
// 176.312 us; speedup vs baseline: 1.0445x; 1.0445x over previous
//
#include <hip/hip_runtime.h>
#include <hip/hip_bf16.h>

// ---------------------------------------------------------------------------
// Fused causal MHA forward: x[B,T,C] fp32, w_qkv[3C,C] fp32, w_out[C,C] fp32
// B=4 T=2048 C=1024 H=16 hd=64.  All matmuls in bf16 MFMA, fp32 accumulate.
// fused convert | GEMM qkv (V^T fused epilogue) | flash-attn | GEMM proj.
// R19 configuration (176.3us measured).  R20's 256x256 gemm reverted:
// grid 384 @ 1 block/CU = 1.5 rounds (half-idle 2nd round) beat the traffic
// saving (L2/L3 already absorbed re-fetch: FETCH was 59.6MB, not 400MB).
// ---------------------------------------------------------------------------

typedef __attribute__((ext_vector_type(8))) short bf16x8;
typedef __attribute__((ext_vector_type(4))) float f32x4;
typedef __attribute__((ext_vector_type(16))) float f32x16;
typedef __attribute__((ext_vector_type(2))) unsigned uint2v;

#define GLOBAL_AS __attribute__((address_space(1)))
#define LDS_AS __attribute__((address_space(3)))

__device__ __forceinline__ unsigned short f2b_rne(float f) {
  unsigned u = __float_as_uint(f);
  unsigned r = u + 0x7fffu + ((u >> 16) & 1u);
  return (unsigned short)(r >> 16);
}

__device__ __forceinline__ unsigned cvt_pk_bf16(float lo, float hi) {
  unsigned r;
  asm("v_cvt_pk_bf16_f32 %0, %1, %2" : "=v"(r) : "v"(lo), "v"(hi));
  return r;
}

__device__ __forceinline__ void gload_lds16(const void* g, void* l) {
  __builtin_amdgcn_global_load_lds((const GLOBAL_AS void*)g, (LDS_AS void*)l, 16, 0, 0);
}

// ---------------------------------------------------------------------------
// Fused fp32 -> bf16 conversion of all three inputs.
// ---------------------------------------------------------------------------
__global__ void fused_convert(const float* __restrict__ x,
                              const float* __restrict__ wqkv,
                              const float* __restrict__ wout,
                              unsigned short* __restrict__ xb,
                              unsigned short* __restrict__ wqkvb,
                              unsigned short* __restrict__ woutb) {
  const int nx = 8192 * 1024 / 4, nq = 3072 * 1024 / 4, nw = 1024 * 1024 / 4;
  const int ntot = nx + nq + nw;
  int i = blockIdx.x * blockDim.x + threadIdx.x;
  int stride = gridDim.x * blockDim.x;
  for (; i < ntot; i += stride) {
    const float* src;
    unsigned short* dst;
    int j = i;
    if (j < nx) {
      src = x; dst = xb;
    } else if ((j -= nx) < nq) {
      src = wqkv; dst = wqkvb;
    } else {
      j -= nq; src = wout; dst = woutb;
    }
    float4 v = reinterpret_cast<const float4*>(src)[j];
    ushort4 o;
    o.x = f2b_rne(v.x); o.y = f2b_rne(v.y);
    o.z = f2b_rne(v.z); o.w = f2b_rne(v.w);
    reinterpret_cast<ushort4*>(dst)[j] = o;
  }
}

// ---------------------------------------------------------------------------
// Big GEMM template: C[M,N] = A[M,1024] * B[N,1024]^T.
// 256x128 tile, 8 waves (4Mx2N), BK=64, mfma_32x32x16, counted-vmcnt loop.
// MODE 1 (qkv): bf16 out; V-blocks (n0>=2048) store TRANSPOSED into
// vt[bh][d][T] via a 64KB LDS bounce (coalesced both sides) and skip the
// qkv store.  MODE 0 (proj): fp32 out.
// ---------------------------------------------------------------------------
template <int N, int MODE>
__global__ __launch_bounds__(512)
void gemm_big(const unsigned short* __restrict__ A,
              const unsigned short* __restrict__ B,
              void* __restrict__ Cout, unsigned short* __restrict__ vt) {
  const int K = 1024;
  __shared__ __align__(16) unsigned short As[2][2][128 * 64];
  __shared__ __align__(16) unsigned short Bs[2][128 * 64];

  const int tid = threadIdx.x, wid = tid >> 6, lane = tid & 63;
  const int l31 = lane & 31, h = lane >> 5;
  const int NBX = N / 128;
  const int nwg8 = (int)gridDim.x >> 3;
  const int wgid = ((int)blockIdx.x & 7) * nwg8 + ((int)blockIdx.x >> 3);
  const int bx = wgid % NBX, by = wgid / NBX;
  const int m0 = by * 256, n0 = bx * 128;
  const int wr = wid >> 1, wc = wid & 1;

  auto stage = [&](int t, int buf) {
    const int k0 = t * 64;
    const int r8 = lane >> 3;
    const int blk = (lane & 7) ^ r8;
#pragma unroll
    for (int hh = 0; hh < 2; ++hh)
#pragma unroll
      for (int r = 0; r < 2; ++r) {
        int row = r * 64 + wid * 8 + r8;
        gload_lds16(A + (size_t)(m0 + hh * 128 + row) * K + k0 + blk * 8,
                    &As[buf][hh][r * 4096 + wid * 512]);
      }
#pragma unroll
    for (int r = 0; r < 2; ++r) {
      int row = r * 64 + wid * 8 + r8;
      gload_lds16(B + (size_t)(n0 + row) * K + k0 + blk * 8,
                  &Bs[buf][r * 4096 + wid * 512]);
    }
  };

  f32x16 acc[2][2] = {};

  stage(0, 0);

  int cur = 0;
  for (int t = 0; t < 16; ++t) {
    __builtin_amdgcn_s_barrier();
    if (t + 1 < 16) {
      stage(t + 1, cur ^ 1);
      asm volatile("s_waitcnt vmcnt(6)" ::: "memory");
    } else {
      asm volatile("s_waitcnt vmcnt(0)" ::: "memory");
    }
    __builtin_amdgcn_s_barrier();
    __builtin_amdgcn_sched_barrier(0);

    bf16x8 af[2][4], bfr[2][4];
#pragma unroll
    for (int mi = 0; mi < 2; ++mi) {
      int row = (wr & 1) * 64 + mi * 32 + l31;
#pragma unroll
      for (int ks = 0; ks < 4; ++ks) {
        int chunk = (ks * 2 + h) ^ (row & 7);
        af[mi][ks] = *(const bf16x8*)&As[cur][wr >> 1][row * 64 + chunk * 8];
      }
    }
#pragma unroll
    for (int ni = 0; ni < 2; ++ni) {
      int row = wc * 64 + ni * 32 + l31;
#pragma unroll
      for (int ks = 0; ks < 4; ++ks) {
        int chunk = (ks * 2 + h) ^ (row & 7);
        bfr[ni][ks] = *(const bf16x8*)&Bs[cur][row * 64 + chunk * 8];
      }
    }
    __builtin_amdgcn_s_setprio(1);
#pragma unroll
    for (int ks = 0; ks < 4; ++ks)
#pragma unroll
      for (int mi = 0; mi < 2; ++mi)
#pragma unroll
        for (int ni = 0; ni < 2; ++ni)
          acc[mi][ni] = __builtin_amdgcn_mfma_f32_32x32x16_bf16(
              af[mi][ks], bfr[ni][ks], acc[mi][ni], 0, 0, 0);
    __builtin_amdgcn_s_setprio(0);
    cur ^= 1;
  }

  if (MODE == 1 && n0 >= 2048) {
    // ---- fused V^T epilogue: acc -> LDS (swizzled) -> vt coalesced ----
    unsigned short(*Ts)[128] = (unsigned short(*)[128]) & As[0][0][0];
    __syncthreads();  // all waves done reading staged LDS
#pragma unroll
    for (int mi = 0; mi < 2; ++mi)
#pragma unroll
      for (int ni = 0; ni < 2; ++ni)
#pragma unroll
        for (int reg = 0; reg < 16; ++reg) {
          int row = wr * 64 + mi * 32 + (reg & 3) + 8 * (reg >> 2) + 4 * h;
          int col = wc * 64 + ni * 32 + l31;
          int c8 = (col >> 3) ^ (row & 15);
          Ts[row][c8 * 8 + (col & 7)] = f2b_rne(acc[mi][ni][reg]);
        }
    __syncthreads();
    const int chbase = n0 - 2048;
    const int bq = m0 >> 11, toff = m0 & 2047;
    const int ch = tid >> 2, tb = tid & 3;
    const int hh = (chbase + ch) >> 6, d = ch & 63;
    unsigned short* dst =
        vt + ((size_t)(bq * 16 + hh) * 64 + d) * 2048 + toff;
#pragma unroll
    for (int i = 0; i < 8; ++i) {
      int t0 = tb * 64 + i * 8;
      union { unsigned short s[8]; bf16x8 v; } o;
#pragma unroll
      for (int k = 0; k < 8; ++k) {
        int row = t0 + k;
        o.s[k] = Ts[row][(((ch >> 3) ^ (row & 15)) * 8) + (ch & 7)];
      }
      *(bf16x8*)(dst + t0) = o.v;
    }
  } else {
#pragma unroll
    for (int mi = 0; mi < 2; ++mi)
#pragma unroll
      for (int ni = 0; ni < 2; ++ni)
#pragma unroll
        for (int reg = 0; reg < 16; ++reg) {
          int row = m0 + wr * 64 + mi * 32 + (reg & 3) + 8 * (reg >> 2) + 4 * h;
          int col = n0 + wc * 64 + ni * 32 + l31;
          if (MODE == 1)
            ((unsigned short*)Cout)[(size_t)row * N + col] =
                f2b_rne(acc[mi][ni][reg]);
          else
            ((float*)Cout)[(size_t)row * N + col] = acc[mi][ni][reg];
        }
  }
}

// ---------------------------------------------------------------------------
// Flash attention fwd, causal; swapped-QK^T 32x32; 64 q-rows per wave.
// Super-tile staging: 128 kv rows per barrier-pair (2x64 compute passes).
// Static XCD map.  (unchanged R17: 79.0us measured)
// ---------------------------------------------------------------------------
__global__ __launch_bounds__(256, 2)
void attn_fwd(const unsigned short* __restrict__ qkv,
              const unsigned short* __restrict__ vt,
              unsigned short* __restrict__ out) {
  const int T = 2048, C3 = 3072;
  __shared__ __align__(16) unsigned short Ks[2][128][64];  // [kv][d] swizzled
  __shared__ __align__(16) unsigned short Vs[2][64][128];  // [d][kv] swizzled
  __shared__ float Bc[4][32];  // per-wave broadcast (wave-private)

  const int tid = threadIdx.x, w = tid >> 6, lane = tid & 63;
  const int l31 = lane & 31, h = lane >> 5;
  const int wgid = (blockIdx.x & 7) * 64 + (blockIdx.x >> 3);
  const int local = wgid & 63, xcd = wgid >> 6;
  const int qidx = local >> 3, bhl = local & 7;
  const int bh = xcd * 8 + bhl;
  const int qt = (qidx < 4) ? (7 - qidx) : (qidx - 4);
  const int b = bh >> 4, hed = bh & 15;
  const int qw = qt * 256 + w * 64;
  const size_t rowbase = (size_t)b * T * C3;
  const int hoff = hed * 64;
  const unsigned short* vbase = vt + (size_t)bh * 64 * 2048;
  const float c2 = 0.18033688f;  // 0.125 * log2(e)

  auto stageK = [&](int kv0, int buf) {
#pragma unroll
    for (int pp = 0; pp < 4; ++pp) {
      int chunk = w * 4 + pp;
      int row = chunk * 8 + (lane >> 3);
      int blk = (lane & 7) ^ (lane >> 3);
      gload_lds16(
          qkv + rowbase + (size_t)(kv0 + row) * C3 + 1024 + hoff + blk * 8,
          &Ks[buf][chunk * 8][0]);
    }
  };
  auto stageV = [&](int kv0, int buf) {
#pragma unroll
    for (int pp = 0; pp < 4; ++pp) {
      int c = w * 4 + pp;
      int d = c * 4 + (lane >> 4);
      int pos = lane & 15;
      int kvb = (pos & 8) | ((pos & 7) ^ (d & 7));
      gload_lds16(vbase + (size_t)d * 2048 + kv0 + kvb * 8,
                  &Vs[buf][c * 4][0]);
    }
  };

  bf16x8 qf0[4], qf1[4];
  {
    const unsigned short* qp0 =
        qkv + rowbase + (size_t)(qw + l31) * C3 + hoff + h * 8;
    const unsigned short* qp1 = qp0 + 32 * C3;
#pragma unroll
    for (int s = 0; s < 4; ++s) {
      qf0[s] = *(const bf16x8*)(qp0 + 16 * s);
      qf1[s] = *(const bf16x8*)(qp1 + 16 * s);
    }
  }

  f32x16 oacc0[2] = {}, oacc1[2] = {};
  float mr0 = -1e30f, mr1 = -1e30f, sum0 = 0.f, sum1 = 0.f;

  stageK(0, 0);
  stageV(0, 0);

  auto do_half = [&](f32x16 (&sacc)[2], int qx, float& mr, float& sm,
                     f32x16 (&oc)[2], bool first, int kvp, int cur, int vofs) {
    if (kvp + 64 > qx) {
      int q_abs = qx + l31;
#pragma unroll
      for (int kt = 0; kt < 2; ++kt)
#pragma unroll
        for (int r = 0; r < 16; ++r) {
          int kv_abs = kvp + kt * 32 + (r & 3) + 8 * (r >> 2) + 4 * h;
          if (kv_abs > q_abs) sacc[kt][r] = -1e30f;
        }
    }
    float mx[8];
#pragma unroll
    for (int g = 0; g < 8; ++g)
      mx[g] = fmaxf(fmaxf(sacc[g >> 2][(g & 3) * 4 + 0],
                          sacc[g >> 2][(g & 3) * 4 + 1]),
                    fmaxf(sacc[g >> 2][(g & 3) * 4 + 2],
                          sacc[g >> 2][(g & 3) * 4 + 3]));
    float tm = fmaxf(fmaxf(fmaxf(mx[0], mx[1]), fmaxf(mx[2], mx[3])),
                     fmaxf(fmaxf(mx[4], mx[5]), fmaxf(mx[6], mx[7])));
    tm = fmaxf(tm, __shfl_xor(tm, 32));
    if (first) {
      mr = tm;
    } else if (!__all(tm <= mr + 16.0f)) {
      float mnew = fmaxf(mr, tm);
      float corr = __builtin_amdgcn_exp2f((mr - mnew) * c2);
      sm *= corr;
      if (h == 0) Bc[w][l31] = corr;
      mr = mnew;
      asm volatile("s_waitcnt lgkmcnt(0)" ::: "memory");
#pragma unroll
      for (int r = 0; r < 16; ++r) {
        float cr = Bc[w][(r & 3) + 8 * (r >> 2) + 4 * h];
        oc[0][r] *= cr;
        oc[1][r] *= cr;
      }
    }
    float m2 = mr * c2;
    float s0 = 0.f, s1 = 0.f, s2 = 0.f, s3 = 0.f;
#pragma unroll
    for (int kt = 0; kt < 2; ++kt)
#pragma unroll
      for (int r = 0; r < 16; r += 4) {
        float p0 = __builtin_amdgcn_exp2f(fmaf(sacc[kt][r + 0], c2, -m2));
        float p1 = __builtin_amdgcn_exp2f(fmaf(sacc[kt][r + 1], c2, -m2));
        float p2 = __builtin_amdgcn_exp2f(fmaf(sacc[kt][r + 2], c2, -m2));
        float p3 = __builtin_amdgcn_exp2f(fmaf(sacc[kt][r + 3], c2, -m2));
        sacc[kt][r + 0] = p0; sacc[kt][r + 1] = p1;
        sacc[kt][r + 2] = p2; sacc[kt][r + 3] = p3;
        s0 += p0; s1 += p1; s2 += p2; s3 += p3;
      }
    float sl = (s0 + s1) + (s2 + s3);
    sm += sl + __shfl_xor(sl, 32);
    unsigned pk[16];
#pragma unroll
    for (int kt = 0; kt < 2; ++kt)
#pragma unroll
      for (int r = 0; r < 16; r += 2)
        pk[kt * 8 + (r >> 1)] = cvt_pk_bf16(sacc[kt][r], sacc[kt][r + 1]);
    __builtin_amdgcn_s_setprio(1);
#pragma unroll
    for (int sg = 0; sg < 4; ++sg) {
      const int kt = sg >> 1, s = sg & 1;
      const int base = kt * 8 + 4 * s;
      uint2v r02 = __builtin_amdgcn_permlane32_swap(pk[base], pk[base + 2],
                                                    false, false);
      uint2v r13 = __builtin_amdgcn_permlane32_swap(pk[base + 1], pk[base + 3],
                                                    false, false);
      union { unsigned u[4]; bf16x8 v; } Afr;
      Afr.u[0] = r02.x; Afr.u[1] = r13.x;
      Afr.u[2] = r02.y; Afr.u[3] = r13.y;
#pragma unroll
      for (int dt = 0; dt < 2; ++dt) {
        int d = dt * 32 + l31;
        int blk = (2 * sg + h) ^ (d & 7);
        bf16x8 vf = *(const bf16x8*)&Vs[cur][d][vofs + blk * 8];
        oc[dt] = __builtin_amdgcn_mfma_f32_32x32x16_bf16(Afr.v, vf,
                                                         oc[dt], 0, 0, 0);
      }
    }
    __builtin_amdgcn_s_setprio(0);
  };

  int cur = 0;
  const int nsup = 2 * qt + 2;  // super-tiles of 128 kv
  for (int t = 0; t < nsup; ++t) {
    const int kv0 = t * 128;
    __builtin_amdgcn_s_barrier();
    if (t + 1 < nsup) {
      stageK(kv0 + 128, cur ^ 1);
      stageV(kv0 + 128, cur ^ 1);
      asm volatile("s_waitcnt vmcnt(8)" ::: "memory");
    } else {
      asm volatile("s_waitcnt vmcnt(0)" ::: "memory");
    }
    __builtin_amdgcn_s_barrier();
    __builtin_amdgcn_sched_barrier(0);

#pragma unroll
    for (int p = 0; p < 2; ++p) {
      const int kvp = kv0 + p * 64;
      if (kvp <= qw) {
        f32x16 sacc0[2] = {}, sacc1[2] = {};
        __builtin_amdgcn_s_setprio(1);
#pragma unroll
        for (int s = 0; s < 4; ++s) {
#pragma unroll
          for (int kt = 0; kt < 2; ++kt) {
            int row = kt * 32 + l31;
            int blk = (2 * s + h) ^ (row & 7);
            bf16x8 kf = *(const bf16x8*)&Ks[cur][p * 64 + row][blk * 8];
            sacc0[kt] = __builtin_amdgcn_mfma_f32_32x32x16_bf16(
                kf, qf0[s], sacc0[kt], 0, 0, 0);
            sacc1[kt] = __builtin_amdgcn_mfma_f32_32x32x16_bf16(
                kf, qf1[s], sacc1[kt], 0, 0, 0);
          }
        }
        __builtin_amdgcn_s_setprio(0);
        const bool first = (t == 0 && p == 0);
        do_half(sacc0, qw, mr0, sum0, oacc0, first, kvp, cur, p * 64);
        do_half(sacc1, qw + 32, mr1, sum1, oacc1, first, kvp, cur, p * 64);
      }
    }
    cur ^= 1;
  }

  // epilogue (Bc is wave-private: lgkmcnt suffices, no barriers)
#pragma unroll
  for (int X = 0; X < 2; ++X) {
    float sm = X ? sum1 : sum0;
    if (h == 0) Bc[w][l31] = 1.0f / sm;
    asm volatile("s_waitcnt lgkmcnt(0)" ::: "memory");
#pragma unroll
    for (int r = 0; r < 16; ++r) {
      int ql = (r & 3) + 8 * (r >> 2) + 4 * h;
      float inv = Bc[w][ql];
      int q_abs = qw + 32 * X + ql;
#pragma unroll
      for (int dt = 0; dt < 2; ++dt) {
        float v = (X ? oacc1 : oacc0)[dt][r] * inv;
        out[(size_t)(b * T + q_abs) * 1024 + hoff + dt * 32 + l31] =
            f2b_rne(v);
      }
    }
  }
}

// ---------------------------------------------------------------------------
extern "C" void kernel_launch(void* const* d_in, const int* in_sizes, int n_in,
                              void* d_out, int out_size, void* d_ws,
                              size_t ws_size, hipStream_t stream) {
  const float* x = (const float*)d_in[0];      // [4,2048,1024]
  const float* w_qkv = (const float*)d_in[1];  // [3072,1024]
  const float* w_out = (const float*)d_in[2];  // [1024,1024]
  float* out = (float*)d_out;                  // [4,2048,1024] fp32

  const int M = 8192, C = 1024, C3 = 3072;

  unsigned short* xb = (unsigned short*)d_ws;      // M*C  (reused as attno)
  unsigned short* wqkvb = xb + (size_t)M * C;      // C3*C
  unsigned short* woutb = wqkvb + (size_t)C3 * C;  // C*C
  unsigned short* qkv = woutb + (size_t)C * C;     // M*C3 (V region unused)
  unsigned short* vtb = qkv + (size_t)M * C3;      // B*H*64*T = M*C
  unsigned short* attno = xb;                      // alias: xb dead post-GEMM1

  fused_convert<<<2048, 256, 0, stream>>>(x, w_qkv, w_out, xb, wqkvb, woutb);

  gemm_big<3072, 1><<<768, 512, 0, stream>>>(xb, wqkvb, qkv, vtb);

  attn_fwd<<<512, 256, 0, stream>>>(qkv, vtb, attno);

  gemm_big<1024, 0><<<256, 512, 0, stream>>>(attno, woutb, out, nullptr);
}